// Round 14
// baseline (150.099 us; speedup 1.0000x reference)
//
#include <hip/hip_runtime.h>
#include <hip/hip_bf16.h>
#include <math.h>

#define D    1024
#define C    16
#define N    256
#define TOK  8192   // B*S
#define DH   512    // D/2
#define RT_T 16     // route: tokens per block
#define WLG  160    // worklist slots, stride-8 buckets
#define BCAP 20     // per-bucket capacity (8*20 = 160)

using bf16x8 = __attribute__((ext_vector_type(8))) short;
using f32x4  = __attribute__((ext_vector_type(4))) float;

__device__ __forceinline__ float gelu_exact(float v) {
    return 0.5f * v * (1.0f + erff(v * 0.70710678118654752440f));
}
__device__ __forceinline__ float sigmoidf_(float z) {
    return 1.0f / (1.0f + expf(-z));
}
__device__ __forceinline__ short f2bf(float f) {          // RNE f32->bf16
    unsigned u = __float_as_uint(f);
    unsigned r = u + 0x7FFF + ((u >> 16) & 1);
    return (short)(r >> 16);
}
__device__ __forceinline__ float bf2f(short s) {
    return __uint_as_float(((unsigned)(unsigned short)s) << 16);
}

// async global->LDS, 16B per lane; LDS dest = wave-uniform base + lane*16
__device__ __forceinline__ void gload16(const void* g, void* l) {
    __builtin_amdgcn_global_load_lds(
        (const __attribute__((address_space(1))) unsigned int*)g,
        (__attribute__((address_space(3))) unsigned int*)l, 16, 0, 0);
}

// ---------------------------------------------------------------------------
// prep_all: fused {col_emb norms | x->bf16 | 3x transpose+convert}
// ---------------------------------------------------------------------------
__device__ __forceinline__ void tconv_body(const float* __restrict__ src0,
        short* __restrict__ dst0, int R, int Cc, int bx, int by, int bz,
        float (*tile)[65], int tid) {
    const size_t bofs = (size_t)bz * R * Cc;
    const float* src = src0 + bofs;
    short* dst = dst0 + bofs;
    const int cBase = bx * 64;
    const int rBase = by * 64;
    const int rr = tid >> 4;
    const int cq = (tid & 15) * 4;
    #pragma unroll
    for (int h = 0; h < 4; ++h) {
        const int r = h * 16 + rr;
        const float4 v = *(const float4*)&src[(size_t)(rBase + r) * Cc + cBase + cq];
        tile[r][cq + 0] = v.x; tile[r][cq + 1] = v.y;
        tile[r][cq + 2] = v.z; tile[r][cq + 3] = v.w;
    }
    __syncthreads();
    #pragma unroll
    for (int h = 0; h < 4; ++h) {
        const int cc = h * 16 + rr;
        short4 o;
        o.x = f2bf(tile[cq + 0][cc]);
        o.y = f2bf(tile[cq + 1][cc]);
        o.z = f2bf(tile[cq + 2][cc]);
        o.w = f2bf(tile[cq + 3][cc]);
        *(short4*)&dst[(size_t)(cBase + cc) * R + rBase + cq] = o;
    }
}

__global__ __launch_bounds__(256) void prep_all_kernel(
        const float* __restrict__ x, const float* __restrict__ col_emb,
        const float* __restrict__ gate_w1, const float* __restrict__ W_cols,
        const float* __restrict__ proj_w,
        short* __restrict__ xb, short* __restrict__ w1T,
        short* __restrict__ WcT, short* __restrict__ pwT,
        float* __restrict__ cnorm) {
    __shared__ float tile[64][65];
    const int b = blockIdx.x;
    const int tid = threadIdx.x;
    if (b == 0) {
        const int c = tid >> 4, l = tid & 15;
        float acc = 0.f;
        for (int j = 0; j < 64; ++j) {
            float v = col_emb[c * D + l + 16 * j];
            acc += v * v;
        }
        for (int off = 8; off; off >>= 1) acc += __shfl_xor(acc, off, 16);
        if (l == 0) cnorm[c] = fmaxf(sqrtf(acc), 1e-12f);
    } else if (b < 2049) {
        const int base = (b - 1) * 1024;
        #pragma unroll
        for (int h = 0; h < 4; ++h) {
            const int i = base + h * 256 + tid;
            const float4 v = ((const float4*)x)[i];
            short4 o;
            o.x = f2bf(v.x); o.y = f2bf(v.y); o.z = f2bf(v.z); o.w = f2bf(v.w);
            ((short4*)xb)[i] = o;
        }
    } else if (b < 2177) {
        const int idx = b - 2049;                 // grid (8, 16)
        tconv_body(gate_w1, w1T, D, DH, idx & 7, idx >> 3, 0, tile, tid);
    } else if (b < 3201) {
        const int idx = b - 2177;                 // grid (4, 16, 16)
        tconv_body(W_cols, WcT, D, N, idx & 3, (idx >> 2) & 15, idx >> 6, tile, tid);
    } else {
        const int idx = b - 3201;                 // grid (16, 4, 16)
        tconv_body(proj_w, pwT, N, D, idx & 15, (idx >> 4) & 3, idx >> 6, tile, tid);
    }
}

// ---------------------------------------------------------------------------
// gate GEMM: H = gelu(xb @ w1T^T + b1), 128x64 tile, BK=64, 2x2 waves,
// double-buffered global_load_lds staging (unchanged round-13)
// ---------------------------------------------------------------------------
__global__ __launch_bounds__(256) void gate_mfma_kernel(
        const short* __restrict__ Ag, const short* __restrict__ BTg,
        const float* __restrict__ bias, short* __restrict__ outb) {
    __shared__ short AB[2][(128 + 64) * 64];   // 48 KB total
    const int tid = threadIdx.x;
    const int lane = tid & 63;
    const int wave = tid >> 6;
    const int wr = wave >> 1, wc = wave & 1;

    const size_t m0 = (size_t)blockIdx.x * 128;
    const int n0 = blockIdx.y * 64;

    const int rl = lane >> 3;                 // 0..7
    const int bl = (lane & 7) * 16;
    const char* gAh[4];
    #pragma unroll
    for (int h = 0; h < 4; ++h) {
        const int r = wave * 32 + h * 8 + rl;
        gAh[h] = (const char*)Ag + (m0 + r) * (size_t)(D * 2) + (bl ^ ((r & 7) << 4));
    }
    const char* gBh[2];
    #pragma unroll
    for (int h = 0; h < 2; ++h) {
        const int r = wave * 16 + h * 8 + rl;
        gBh[h] = (const char*)BTg + (size_t)(n0 + r) * (D * 2) + (bl ^ ((r & 7) << 4));
    }

    const int swz = ((lane & 7)) << 4;
    const int kb0 = (lane >> 4) * 16;

    f32x4 acc[4][2] = {};
    {
        char* Ab = (char*)AB[0];
        char* Bb = (char*)AB[0] + 16384;
        #pragma unroll
        for (int h = 0; h < 4; ++h) gload16(gAh[h], Ab + (wave * 32 + h * 8) * 128);
        #pragma unroll
        for (int h = 0; h < 2; ++h) gload16(gBh[h], Bb + (wave * 16 + h * 8) * 128);
    }
    __syncthreads();
    for (int kk = 0; kk < D / 64; ++kk) {
        const int cur = kk & 1;
        if (kk + 1 < D / 64) {
            const int ko = (kk + 1) * 128;
            char* Ab = (char*)AB[cur ^ 1];
            char* Bb = (char*)AB[cur ^ 1] + 16384;
            #pragma unroll
            for (int h = 0; h < 4; ++h) gload16(gAh[h] + ko, Ab + (wave * 32 + h * 8) * 128);
            #pragma unroll
            for (int h = 0; h < 2; ++h) gload16(gBh[h] + ko, Bb + (wave * 16 + h * 8) * 128);
        }
        const char* As = (const char*)AB[cur];
        const char* Bs = As + 16384;
        #pragma unroll
        for (int ks = 0; ks < 2; ++ks) {
            const int kb = kb0 + ks * 64;
            bf16x8 aF[4], bF[2];
            #pragma unroll
            for (int i = 0; i < 4; ++i)
                aF[i] = *(const bf16x8*)(As + (wr * 64 + i * 16 + (lane & 15)) * 128
                                         + (kb ^ swz));
            #pragma unroll
            for (int j = 0; j < 2; ++j)
                bF[j] = *(const bf16x8*)(Bs + (wc * 32 + j * 16 + (lane & 15)) * 128
                                         + (kb ^ swz));
            #pragma unroll
            for (int i = 0; i < 4; ++i)
                #pragma unroll
                for (int j = 0; j < 2; ++j)
                    acc[i][j] = __builtin_amdgcn_mfma_f32_16x16x32_bf16(
                                    aF[i], bF[j], acc[i][j], 0, 0, 0);
        }
        __syncthreads();
    }
    const int crow = (lane >> 4) * 4;
    const int ccol = lane & 15;
    #pragma unroll
    for (int i = 0; i < 4; ++i)
        #pragma unroll
        for (int j = 0; j < 2; ++j) {
            const int n = n0 + wc * 32 + j * 16 + ccol;
            const float bb = bias[n];
            #pragma unroll
            for (int r = 0; r < 4; ++r) {
                const int m = (int)m0 + wr * 64 + i * 16 + crow + r;
                outb[(size_t)m * DH + n] = f2bf(gelu_exact(acc[i][j][r] + bb));
            }
        }
}

// ---------------------------------------------------------------------------
// column GEMM1 (grouped, worklist): 64x64 tile, BK=64, 3-buffer 2-deep
// pipeline with counted vmcnt (never drain to 0 in steady state).
// act = gelu(xb[tok] @ WcT[col]^T + bc)*wgt -> actb[slot]
// ---------------------------------------------------------------------------
__global__ __launch_bounds__(256) void col1_kernel(
        const short* __restrict__ Ag, const short* __restrict__ BTg,
        const float* __restrict__ bias,
        const int* __restrict__ order, const float* __restrict__ wgt,
        const int* __restrict__ wl, short* __restrict__ outb) {
    __shared__ short AB[3][2][64 * 64];       // 48 KB (3 buffers)
    __shared__ int   tokl[64];
    __shared__ float wgl[64];

    const int e = wl[blockIdx.x];
    if (e < 0) return;
    const int col  = e >> 24;
    const int nt   = (e >> 16) & 0xFF;
    const int base = e & 0xFFFF;

    const int tid = threadIdx.x;
    const int lane = tid & 63;
    const int wave = tid >> 6;
    const int wr = wave >> 1, wc = wave & 1;
    const int n0 = blockIdx.y * 64;

    if (tid < 64) {
        const int i = tid < nt ? tid : nt - 1;
        const int t = order[base + i];
        tokl[tid] = t;
        wgl[tid] = wgt[t];
    }
    __syncthreads();          // drains all outstanding vmem -> vmcnt accounting starts at 0

    const int r0 = wave * 16 + (lane >> 3);
    const int r1 = r0 + 8;
    const int bl = (lane & 7) * 16;
    const int b0 = bl ^ ((r0 & 7) << 4);
    const int b1 = bl ^ ((r1 & 7) << 4);
    const char* gA0 = (const char*)Ag + (size_t)tokl[r0] * (D * 2) + b0;
    const char* gA1 = (const char*)Ag + (size_t)tokl[r1] * (D * 2) + b1;
    const size_t bbase = ((size_t)col * N + n0) * (D * 2);
    const char* gB0 = (const char*)BTg + bbase + (size_t)r0 * (D * 2) + b0;
    const char* gB1 = (const char*)BTg + bbase + (size_t)r1 * (D * 2) + b1;
    const int ldsWo = wave * 2048;

    const int mrow = wr * 32 + (lane & 15);
    const int nrow = wc * 32 + (lane & 15);
    const int kb0 = (lane >> 4) * 16;
    const int swm = (mrow & 7) << 4;
    const int swn = (nrow & 7) << 4;

    // stage tile kk into buffer bf: 4 gload16 per thread
    #define C1STAGE(bf, kk) do {                                  \
        const int ko_ = (kk) * 128;                               \
        char* lA_ = (char*)AB[bf][0] + ldsWo;                     \
        char* lB_ = (char*)AB[bf][1] + ldsWo;                     \
        gload16(gA0 + ko_, lA_); gload16(gA1 + ko_, lA_ + 1024);  \
        gload16(gB0 + ko_, lB_); gload16(gB1 + ko_, lB_ + 1024);  \
    } while (0)

    f32x4 acc[2][2] = {};
    C1STAGE(0, 0);
    C1STAGE(1, 1);
    // wait: own 8 outstanding -> 4 (tile0 complete; tile1 still in flight)
    asm volatile("s_waitcnt vmcnt(4)" ::: "memory");
    __builtin_amdgcn_s_barrier();
    asm volatile("" ::: "memory");
    #pragma unroll
    for (int kk = 0; kk < D / 64; ++kk) {
        const int cur = kk % 3;
        if (kk + 2 < D / 64) C1STAGE((kk + 2) % 3, kk + 2);
        const char* As = (const char*)AB[cur][0];
        const char* Bs = (const char*)AB[cur][1];
        #pragma unroll
        for (int ks = 0; ks < 2; ++ks) {
            const int kb = kb0 + ks * 64;
            bf16x8 aF[2], bF[2];
            #pragma unroll
            for (int i = 0; i < 2; ++i)
                aF[i] = *(const bf16x8*)(As + (mrow + i * 16) * 128 + (kb ^ swm));
            #pragma unroll
            for (int j = 0; j < 2; ++j)
                bF[j] = *(const bf16x8*)(Bs + (nrow + j * 16) * 128 + (kb ^ swn));
            #pragma unroll
            for (int i = 0; i < 2; ++i)
                #pragma unroll
                for (int j = 0; j < 2; ++j)
                    acc[i][j] = __builtin_amdgcn_mfma_f32_16x16x32_bf16(
                                    aF[i], bF[j], acc[i][j], 0, 0, 0);
        }
        // per-wave: retire tile kk+1's loads (FIFO); tile kk+2's may stay in flight
        if (kk + 2 < D / 64) asm volatile("s_waitcnt vmcnt(4)" ::: "memory");
        else                 asm volatile("s_waitcnt vmcnt(0)" ::: "memory");
        __builtin_amdgcn_s_barrier();
        asm volatile("" ::: "memory");
    }
    #undef C1STAGE

    const int crow = (lane >> 4) * 4;
    const int ccol = lane & 15;
    #pragma unroll
    for (int i = 0; i < 2; ++i)
        #pragma unroll
        for (int j = 0; j < 2; ++j) {
            const int n = n0 + wc * 32 + j * 16 + ccol;
            const float bb = bias[col * N + n];
            #pragma unroll
            for (int r = 0; r < 4; ++r) {
                const int il = wr * 32 + i * 16 + crow + r;
                if (il < nt) {
                    const float v = gelu_exact(acc[i][j][r] + bb) * wgl[il];
                    outb[(size_t)(base + il) * N + n] = f2bf(v);
                }
            }
        }
}

// ---------------------------------------------------------------------------
// column GEMM2 (proj): 64(m) x 128(n) tile, K=256 (4 steps), dbuf gload.
// A = actb slots (contiguous), B = pwT. Writes ybuf[slot] = bf16(acc + pb).
// (unchanged round-13)
// ---------------------------------------------------------------------------
__global__ __launch_bounds__(256) void proj_kernel(
        const short* __restrict__ Ag, const short* __restrict__ BTg,
        const float* __restrict__ bias, const int* __restrict__ wl,
        short* __restrict__ ybufb) {
    __shared__ short AB[2][(64 + 128) * 64];  // 48 KB (A 8KB + B 16KB per buf)
    const int e = wl[blockIdx.x];
    if (e < 0) return;
    const int col  = e >> 24;
    const int nt   = (e >> 16) & 0xFF;
    const int base = e & 0xFFFF;

    const int tid = threadIdx.x;
    const int lane = tid & 63;
    const int wave = tid >> 6;
    const int wr = wave >> 1, wc = wave & 1;
    const int n0 = blockIdx.y * 128;

    const int rl = lane >> 3;
    const int bl = (lane & 7) * 16;
    const int rA0 = wave * 16 + rl;
    const int rA1 = rA0 + 8;
    const char* gA0 = (const char*)Ag
        + (size_t)(base + min(rA0, nt - 1)) * (N * 2) + (bl ^ ((rA0 & 7) << 4));
    const char* gA1 = (const char*)Ag
        + (size_t)(base + min(rA1, nt - 1)) * (N * 2) + (bl ^ ((rA1 & 7) << 4));
    const size_t bbase = ((size_t)col * D + n0) * (N * 2);
    const char* gBh[4];
    #pragma unroll
    for (int h = 0; h < 4; ++h) {
        const int r = wave * 32 + h * 8 + rl;
        gBh[h] = (const char*)BTg + bbase + (size_t)r * (N * 2) + (bl ^ ((r & 7) << 4));
    }

    const int kb0 = (lane >> 4) * 16;

    f32x4 acc[2][4] = {};
    {
        char* Ab = (char*)AB[0];
        char* Bb = (char*)AB[0] + 8192;
        gload16(gA0, Ab + wave * 2048);
        gload16(gA1, Ab + wave * 2048 + 1024);
        #pragma unroll
        for (int h = 0; h < 4; ++h) gload16(gBh[h], Bb + (wave * 32 + h * 8) * 128);
    }
    __syncthreads();
    #pragma unroll
    for (int kk = 0; kk < N / 64; ++kk) {
        const int cur = kk & 1;
        if (kk + 1 < N / 64) {
            const int ko = (kk + 1) * 128;
            char* Ab = (char*)AB[cur ^ 1];
            char* Bb = (char*)AB[cur ^ 1] + 8192;
            gload16(gA0 + ko, Ab + wave * 2048);
            gload16(gA1 + ko, Ab + wave * 2048 + 1024);
            #pragma unroll
            for (int h = 0; h < 4; ++h) gload16(gBh[h] + ko, Bb + (wave * 32 + h * 8) * 128);
        }
        const char* As = (const char*)AB[cur];
        const char* Bs = As + 8192;
        #pragma unroll
        for (int ks = 0; ks < 2; ++ks) {
            const int kb = kb0 + ks * 64;
            bf16x8 aF[2], bF[4];
            #pragma unroll
            for (int i = 0; i < 2; ++i) {
                const int m = wr * 32 + i * 16 + (lane & 15);
                aF[i] = *(const bf16x8*)(As + m * 128 + (kb ^ ((m & 7) << 4)));
            }
            #pragma unroll
            for (int j = 0; j < 4; ++j) {
                const int n = wc * 64 + j * 16 + (lane & 15);
                bF[j] = *(const bf16x8*)(Bs + n * 128 + (kb ^ ((n & 7) << 4)));
            }
            #pragma unroll
            for (int i = 0; i < 2; ++i)
                #pragma unroll
                for (int j = 0; j < 4; ++j)
                    acc[i][j] = __builtin_amdgcn_mfma_f32_16x16x32_bf16(
                                    aF[i], bF[j], acc[i][j], 0, 0, 0);
        }
        __syncthreads();
    }

    const int crow = (lane >> 4) * 4;
    const int ccol = lane & 15;
    #pragma unroll
    for (int i = 0; i < 2; ++i)
        #pragma unroll
        for (int j = 0; j < 4; ++j) {
            const int dcol = n0 + wc * 64 + j * 16 + ccol;
            const float bb = bias[dcol];
            #pragma unroll
            for (int r = 0; r < 4; ++r) {
                const int il = wr * 32 + i * 16 + crow + r;
                if (il < nt)
                    ybufb[(size_t)(base + il) * D + dcol] = f2bf(acc[i][j][r] + bb);
            }
        }
}

// ---------------------------------------------------------------------------
// route: weights-in-registers, activations streamed coalesced (round-4 winner)
// ---------------------------------------------------------------------------
__global__ __launch_bounds__(256) void route_kernel(
        const float* __restrict__ x, const short* __restrict__ Hb,
        const float* __restrict__ col_emb, const float* __restrict__ cnorm,
        const float* __restrict__ w2, const float* __restrict__ b2,
        int* __restrict__ idx, float* __restrict__ wgt) {
    __shared__ float P[256][33];
    __shared__ float Q[8][33];
    __shared__ float SSW[4];
    __shared__ float FL[RT_T][34];
    const int tid = threadIdx.x;
    const int lane = tid & 63;
    const int t0 = blockIdx.x * RT_T;
    const int swz = (tid & 7) << 2;

    float4 ce[C];
    #pragma unroll
    for (int c = 0; c < C; ++c)
        ce[c] = *(const float4*)&col_emb[c * D + tid * 4];
    float w2r[2][C];
    #pragma unroll
    for (int r2 = 0; r2 < 2; ++r2)
        #pragma unroll
        for (int cq = 0; cq < 4; ++cq) {
            const float4 v = *(const float4*)&w2[(tid * 2 + r2) * C + cq * 4];
            w2r[r2][cq * 4 + 0] = v.x; w2r[r2][cq * 4 + 1] = v.y;
            w2r[r2][cq * 4 + 2] = v.z; w2r[r2][cq * 4 + 3] = v.w;
        }

    for (int ti = 0; ti < RT_T; ++ti) {
        const int t = t0 + ti;
        const float4 xv = *(const float4*)&x[(size_t)t * D + tid * 4];
        const unsigned hu = *(const unsigned*)&Hb[(size_t)t * DH + tid * 2];
        const float h0 = bf2f((short)(hu & 0xffff));
        const float h1 = bf2f((short)(hu >> 16));
        float pv[32];
        #pragma unroll
        for (int c = 0; c < C; ++c)
            pv[c] = xv.x * ce[c].x + xv.y * ce[c].y + xv.z * ce[c].z + xv.w * ce[c].w;
        #pragma unroll
        for (int c = 0; c < C; ++c)
            pv[C + c] = h0 * w2r[0][c] + h1 * w2r[1][c];
        float ssp = xv.x * xv.x + xv.y * xv.y + xv.z * xv.z + xv.w * xv.w;
        #pragma unroll
        for (int off = 32; off; off >>= 1) ssp += __shfl_xor(ssp, off);
        if (lane == 0) SSW[tid >> 6] = ssp;
        #pragma unroll
        for (int c = 0; c < 32; ++c)
            P[tid][c ^ swz] = pv[c];
        __syncthreads();
        {
            const int v = tid & 31, jj = tid >> 5;
            float s = 0.f;
            #pragma unroll
            for (int k = 0; k < 32; ++k) {
                const int row = jj * 32 + k;
                s += P[row][v ^ ((row & 7) << 2)];
            }
            Q[jj][v] = s;
        }
        __syncthreads();
        if (tid < 32) {
            float f = 0.f;
            #pragma unroll
            for (int j2 = 0; j2 < 8; ++j2) f += Q[j2][tid];
            FL[ti][tid] = f;
        } else if (tid == 32) {
            FL[ti][32] = SSW[0] + SSW[1] + SSW[2] + SSW[3];
        }
        __syncthreads();
    }

    if (tid < RT_T) {
        const int t = t0 + tid;
        const float xn = fmaxf(sqrtf(FL[tid][32]), 1e-12f);
        float logit[C];
        #pragma unroll
        for (int c = 0; c < C; ++c)
            logit[c] = FL[tid][c] / (xn * cnorm[c])
                     + sigmoidf_(FL[tid][C + c] + b2[c]);
        float mx = logit[0]; int am = 0;
        #pragma unroll
        for (int c = 1; c < C; ++c)
            if (logit[c] > mx) { mx = logit[c]; am = c; }
        float se = 0.f;
        #pragma unroll
        for (int c = 0; c < C; ++c) se += expf(logit[c] - mx);
        idx[t] = am;
        wgt[t] = 1.f / se;
    }
}

// ---------------------------------------------------------------------------
// histogram (ballot-based) + prefix + packed worklist (single block)
// ---------------------------------------------------------------------------
__global__ __launch_bounds__(256) void hist_kernel(const int* __restrict__ idx,
        int* __restrict__ cursor, int* __restrict__ wl) {
    __shared__ int h[C];
    const int tid = threadIdx.x;
    const int lane = tid & 63;
    const int wave = tid >> 6;
    if (tid < C) h[tid] = 0;
    for (int i = tid; i < WLG; i += 256) wl[i] = -1;
    __syncthreads();
    int cnt = 0;
    for (int t0 = wave * 64; t0 < TOK; t0 += 256) {
        const int c = idx[t0 + lane];
        #pragma unroll
        for (int cc = 0; cc < C; ++cc) {
            const unsigned long long m = __ballot(c == cc);
            if (lane == cc) cnt += (int)__popcll(m);
        }
    }
    if (lane < C) atomicAdd(&h[lane], cnt);
    __syncthreads();
    if (tid == 0) {
        int s = 0;
        int slots[8] = {0, 0, 0, 0, 0, 0, 0, 0};
        for (int c = 0; c < C; ++c) {
            cursor[c] = s;
            for (int st = 0; st < h[c]; st += 64) {
                const int ntg = min(64, h[c] - st);
                int b = c & 7;
                while (slots[b] >= BCAP) b = (b + 1) & 7;
                wl[slots[b] * 8 + b] = (c << 24) | (ntg << 16) | (s + st);
                slots[b]++;
            }
            s += h[c];
        }
    }
}

// ---------------------------------------------------------------------------
// scatter: block-local ranges -> 16 global atomics per block
// ---------------------------------------------------------------------------
__global__ __launch_bounds__(256) void scatter_kernel(const int* __restrict__ idx,
        int* __restrict__ cursor, int* __restrict__ order) {
    __shared__ int lh[C];
    __shared__ int lbase[C];
    const int tid = threadIdx.x;
    const int t = blockIdx.x * 256 + tid;
    if (tid < C) lh[tid] = 0;
    __syncthreads();
    const int c = idx[t];
    const int p = atomicAdd(&lh[c], 1);
    __syncthreads();
    if (tid < C) lbase[tid] = atomicAdd(&cursor[tid], lh[tid]);
    __syncthreads();
    order[lbase[c] + p] = t;
}

// ---------------------------------------------------------------------------
// layernorm + residual + slot->token permutation:
// block s: row = order[s]; y = bf2f(ybufb[s]) + x[row]; out[row] = LN(y)
// ---------------------------------------------------------------------------
__global__ __launch_bounds__(256) void ln_kernel(const short* __restrict__ ybufb,
        const float* __restrict__ x, const int* __restrict__ order,
        const float* __restrict__ g, const float* __restrict__ b,
        float* __restrict__ out) {
    __shared__ float wr_[4], wr2[4];
    const int s0 = blockIdx.x, tid = threadIdx.x;
    const int row = order[s0];
    const short4 ys = *(const short4*)&ybufb[(size_t)s0 * D + tid * 4];
    const float4 xv = *(const float4*)&x[(size_t)row * D + tid * 4];
    float4 v;
    v.x = bf2f(ys.x) + xv.x; v.y = bf2f(ys.y) + xv.y;
    v.z = bf2f(ys.z) + xv.z; v.w = bf2f(ys.w) + xv.w;
    float s = v.x + v.y + v.z + v.w;
    float s2 = v.x * v.x + v.y * v.y + v.z * v.z + v.w * v.w;
    for (int off = 32; off; off >>= 1) { s += __shfl_xor(s, off); s2 += __shfl_xor(s2, off); }
    if ((tid & 63) == 0) { wr_[tid >> 6] = s; wr2[tid >> 6] = s2; }
    __syncthreads();
    const float sum = wr_[0] + wr_[1] + wr_[2] + wr_[3];
    const float sum2 = wr2[0] + wr2[1] + wr2[2] + wr2[3];
    const float mu = sum * (1.f / D);
    const float var = sum2 * (1.f / D) - mu * mu;
    const float inv = rsqrtf(var + 1e-5f);
    const float4 g4 = *(const float4*)&g[tid * 4];
    const float4 b4 = *(const float4*)&b[tid * 4];
    float4 o;
    o.x = (v.x - mu) * inv * g4.x + b4.x;
    o.y = (v.y - mu) * inv * g4.y + b4.y;
    o.z = (v.z - mu) * inv * g4.z + b4.z;
    o.w = (v.w - mu) * inv * g4.w + b4.w;
    *(float4*)&out[(size_t)row * D + tid * 4] = o;
}

// ---------------------------------------------------------------------------
extern "C" void kernel_launch(void* const* d_in, const int* in_sizes, int n_in,
                              void* d_out, int out_size, void* d_ws, size_t ws_size,
                              hipStream_t stream) {
    const float* x       = (const float*)d_in[0];
    const float* col_emb = (const float*)d_in[1];
    const float* gate_w1 = (const float*)d_in[2];
    const float* gate_b1 = (const float*)d_in[3];
    const float* gate_w2 = (const float*)d_in[4];
    const float* gate_b2 = (const float*)d_in[5];
    const float* W_cols  = (const float*)d_in[6];
    const float* b_cols  = (const float*)d_in[7];
    const float* proj_w  = (const float*)d_in[8];
    const float* proj_b  = (const float*)d_in[9];
    const float* ln_g    = (const float*)d_in[10];
    const float* ln_b    = (const float*)d_in[11];
    float* out = (float*)d_out;

    char* w = (char*)d_ws;
    short* xb    = (short*)w;  w += (size_t)TOK * D * 2;           // 16 MB
    short* Hb    = (short*)w;  w += (size_t)TOK * DH * 2;          //  8 MB
    short* actb  = (short*)w;  w += (size_t)TOK * N * 2 + 65536;   //  4 MB + slack
    short* w1T   = (short*)w;  w += (size_t)DH * D * 2;            //  1 MB
    short* WcT   = (short*)w;  w += (size_t)C * N * D * 2;         //  8 MB
    short* pwT   = (short*)w;  w += (size_t)C * D * N * 2;         //  8 MB
    short* ybufb = (short*)w;  w += (size_t)TOK * D * 2;           // 16 MB
    float* wgt   = (float*)w;  w += TOK * 4;
    float* cnorm = (float*)w;  w += 64;
    int*   idx   = (int*)w;    w += TOK * 4;
    int*   order = (int*)w;    w += TOK * 4;
    int*   cursor= (int*)w;    w += 64;
    int*   wl    = (int*)w;    w += WLG * 4;

    hipLaunchKernelGGL(prep_all_kernel, dim3(4225), dim3(256), 0, stream,
                       x, col_emb, gate_w1, W_cols, proj_w,
                       xb, w1T, WcT, pwT, cnorm);
    hipLaunchKernelGGL(gate_mfma_kernel, dim3(TOK / 128, DH / 64), dim3(256), 0, stream,
                       xb, w1T, gate_b1, Hb);
    hipLaunchKernelGGL(route_kernel, dim3(TOK / RT_T), dim3(256), 0, stream,
                       x, Hb, col_emb, cnorm, gate_w2, gate_b2, idx, wgt);
    hipLaunchKernelGGL(hist_kernel, dim3(1), dim3(256), 0, stream, idx, cursor, wl);
    hipLaunchKernelGGL(scatter_kernel, dim3(TOK / 256), dim3(256), 0, stream,
                       idx, cursor, order);
    hipLaunchKernelGGL(col1_kernel, dim3(WLG, N / 64), dim3(256), 0, stream,
                       xb, WcT, b_cols, order, wgt, wl, actb);
    hipLaunchKernelGGL(proj_kernel, dim3(WLG, D / 128), dim3(256), 0, stream,
                       actb, pwT, proj_b, wl, ybufb);
    hipLaunchKernelGGL(ln_kernel, dim3(TOK), dim3(256), 0, stream,
                       ybufb, x, order, ln_g, ln_b, out);
}

// Round 15
// 147.285 us; speedup vs baseline: 1.0191x; 1.0191x over previous
//
#include <hip/hip_runtime.h>
#include <hip/hip_bf16.h>
#include <math.h>

#define D    1024
#define C    16
#define N    256
#define TOK  8192   // B*S
#define DH   512    // D/2
#define RT_T 16     // route: tokens per block
#define WLG  160    // worklist slots, stride-8 buckets
#define BCAP 20     // per-bucket capacity (8*20 = 160)

using bf16x8 = __attribute__((ext_vector_type(8))) short;
using f32x4  = __attribute__((ext_vector_type(4))) float;

__device__ __forceinline__ float gelu_exact(float v) {
    return 0.5f * v * (1.0f + erff(v * 0.70710678118654752440f));
}
__device__ __forceinline__ float sigmoidf_(float z) {
    return 1.0f / (1.0f + expf(-z));
}
__device__ __forceinline__ short f2bf(float f) {          // RNE f32->bf16
    unsigned u = __float_as_uint(f);
    unsigned r = u + 0x7FFF + ((u >> 16) & 1);
    return (short)(r >> 16);
}
__device__ __forceinline__ float bf2f(short s) {
    return __uint_as_float(((unsigned)(unsigned short)s) << 16);
}

// async global->LDS, 16B per lane; LDS dest = wave-uniform base + lane*16
__device__ __forceinline__ void gload16(const void* g, void* l) {
    __builtin_amdgcn_global_load_lds(
        (const __attribute__((address_space(1))) unsigned int*)g,
        (__attribute__((address_space(3))) unsigned int*)l, 16, 0, 0);
}

// ---------------------------------------------------------------------------
// prep_all: fused {col_emb norms | x->bf16 | 3x transpose+convert}
// ---------------------------------------------------------------------------
__device__ __forceinline__ void tconv_body(const float* __restrict__ src0,
        short* __restrict__ dst0, int R, int Cc, int bx, int by, int bz,
        float (*tile)[65], int tid) {
    const size_t bofs = (size_t)bz * R * Cc;
    const float* src = src0 + bofs;
    short* dst = dst0 + bofs;
    const int cBase = bx * 64;
    const int rBase = by * 64;
    const int rr = tid >> 4;
    const int cq = (tid & 15) * 4;
    #pragma unroll
    for (int h = 0; h < 4; ++h) {
        const int r = h * 16 + rr;
        const float4 v = *(const float4*)&src[(size_t)(rBase + r) * Cc + cBase + cq];
        tile[r][cq + 0] = v.x; tile[r][cq + 1] = v.y;
        tile[r][cq + 2] = v.z; tile[r][cq + 3] = v.w;
    }
    __syncthreads();
    #pragma unroll
    for (int h = 0; h < 4; ++h) {
        const int cc = h * 16 + rr;
        short4 o;
        o.x = f2bf(tile[cq + 0][cc]);
        o.y = f2bf(tile[cq + 1][cc]);
        o.z = f2bf(tile[cq + 2][cc]);
        o.w = f2bf(tile[cq + 3][cc]);
        *(short4*)&dst[(size_t)(cBase + cc) * R + rBase + cq] = o;
    }
}

__global__ __launch_bounds__(256) void prep_all_kernel(
        const float* __restrict__ x, const float* __restrict__ col_emb,
        const float* __restrict__ gate_w1, const float* __restrict__ W_cols,
        const float* __restrict__ proj_w,
        short* __restrict__ xb, short* __restrict__ w1T,
        short* __restrict__ WcT, short* __restrict__ pwT,
        float* __restrict__ cnorm) {
    __shared__ float tile[64][65];
    const int b = blockIdx.x;
    const int tid = threadIdx.x;
    if (b == 0) {
        const int c = tid >> 4, l = tid & 15;
        float acc = 0.f;
        for (int j = 0; j < 64; ++j) {
            float v = col_emb[c * D + l + 16 * j];
            acc += v * v;
        }
        for (int off = 8; off; off >>= 1) acc += __shfl_xor(acc, off, 16);
        if (l == 0) cnorm[c] = fmaxf(sqrtf(acc), 1e-12f);
    } else if (b < 2049) {
        const int base = (b - 1) * 1024;
        #pragma unroll
        for (int h = 0; h < 4; ++h) {
            const int i = base + h * 256 + tid;
            const float4 v = ((const float4*)x)[i];
            short4 o;
            o.x = f2bf(v.x); o.y = f2bf(v.y); o.z = f2bf(v.z); o.w = f2bf(v.w);
            ((short4*)xb)[i] = o;
        }
    } else if (b < 2177) {
        const int idx = b - 2049;                 // grid (8, 16)
        tconv_body(gate_w1, w1T, D, DH, idx & 7, idx >> 3, 0, tile, tid);
    } else if (b < 3201) {
        const int idx = b - 2177;                 // grid (4, 16, 16)
        tconv_body(W_cols, WcT, D, N, idx & 3, (idx >> 2) & 15, idx >> 6, tile, tid);
    } else {
        const int idx = b - 3201;                 // grid (16, 4, 16)
        tconv_body(proj_w, pwT, N, D, idx & 15, (idx >> 4) & 3, idx >> 6, tile, tid);
    }
}

// ---------------------------------------------------------------------------
// gate GEMM: H = gelu(xb @ w1T^T + b1), 128x64 tile, BK=64, 2x2 waves,
// double-buffered global_load_lds staging
// ---------------------------------------------------------------------------
__global__ __launch_bounds__(256) void gate_mfma_kernel(
        const short* __restrict__ Ag, const short* __restrict__ BTg,
        const float* __restrict__ bias, short* __restrict__ outb) {
    __shared__ short AB[2][(128 + 64) * 64];   // 48 KB total
    const int tid = threadIdx.x;
    const int lane = tid & 63;
    const int wave = tid >> 6;
    const int wr = wave >> 1, wc = wave & 1;

    const size_t m0 = (size_t)blockIdx.x * 128;
    const int n0 = blockIdx.y * 64;

    const int rl = lane >> 3;                 // 0..7
    const int bl = (lane & 7) * 16;
    const char* gAh[4];
    #pragma unroll
    for (int h = 0; h < 4; ++h) {
        const int r = wave * 32 + h * 8 + rl;
        gAh[h] = (const char*)Ag + (m0 + r) * (size_t)(D * 2) + (bl ^ ((r & 7) << 4));
    }
    const char* gBh[2];
    #pragma unroll
    for (int h = 0; h < 2; ++h) {
        const int r = wave * 16 + h * 8 + rl;
        gBh[h] = (const char*)BTg + (size_t)(n0 + r) * (D * 2) + (bl ^ ((r & 7) << 4));
    }

    const int swz = ((lane & 7)) << 4;
    const int kb0 = (lane >> 4) * 16;

    f32x4 acc[4][2] = {};
    {
        char* Ab = (char*)AB[0];
        char* Bb = (char*)AB[0] + 16384;
        #pragma unroll
        for (int h = 0; h < 4; ++h) gload16(gAh[h], Ab + (wave * 32 + h * 8) * 128);
        #pragma unroll
        for (int h = 0; h < 2; ++h) gload16(gBh[h], Bb + (wave * 16 + h * 8) * 128);
    }
    __syncthreads();
    for (int kk = 0; kk < D / 64; ++kk) {
        const int cur = kk & 1;
        if (kk + 1 < D / 64) {
            const int ko = (kk + 1) * 128;
            char* Ab = (char*)AB[cur ^ 1];
            char* Bb = (char*)AB[cur ^ 1] + 16384;
            #pragma unroll
            for (int h = 0; h < 4; ++h) gload16(gAh[h] + ko, Ab + (wave * 32 + h * 8) * 128);
            #pragma unroll
            for (int h = 0; h < 2; ++h) gload16(gBh[h] + ko, Bb + (wave * 16 + h * 8) * 128);
        }
        const char* As = (const char*)AB[cur];
        const char* Bs = As + 16384;
        #pragma unroll
        for (int ks = 0; ks < 2; ++ks) {
            const int kb = kb0 + ks * 64;
            bf16x8 aF[4], bF[2];
            #pragma unroll
            for (int i = 0; i < 4; ++i)
                aF[i] = *(const bf16x8*)(As + (wr * 64 + i * 16 + (lane & 15)) * 128
                                         + (kb ^ swz));
            #pragma unroll
            for (int j = 0; j < 2; ++j)
                bF[j] = *(const bf16x8*)(Bs + (wc * 32 + j * 16 + (lane & 15)) * 128
                                         + (kb ^ swz));
            #pragma unroll
            for (int i = 0; i < 4; ++i)
                #pragma unroll
                for (int j = 0; j < 2; ++j)
                    acc[i][j] = __builtin_amdgcn_mfma_f32_16x16x32_bf16(
                                    aF[i], bF[j], acc[i][j], 0, 0, 0);
        }
        __syncthreads();
    }
    const int crow = (lane >> 4) * 4;
    const int ccol = lane & 15;
    #pragma unroll
    for (int i = 0; i < 4; ++i)
        #pragma unroll
        for (int j = 0; j < 2; ++j) {
            const int n = n0 + wc * 32 + j * 16 + ccol;
            const float bb = bias[n];
            #pragma unroll
            for (int r = 0; r < 4; ++r) {
                const int m = (int)m0 + wr * 64 + i * 16 + crow + r;
                outb[(size_t)m * DH + n] = f2bf(gelu_exact(acc[i][j][r] + bb));
            }
        }
}

// ---------------------------------------------------------------------------
// column GEMM1 (grouped, worklist): 64x64 tile, BK=64, dbuf gload (round-8)
// act = gelu(xb[tok] @ WcT[col]^T + bc)*wgt -> actb[slot]
// ---------------------------------------------------------------------------
__global__ __launch_bounds__(256) void col1_kernel(
        const short* __restrict__ Ag, const short* __restrict__ BTg,
        const float* __restrict__ bias,
        const int* __restrict__ order, const float* __restrict__ wgt,
        const int* __restrict__ wl, short* __restrict__ outb) {
    __shared__ short AB[2][2][64 * 64];       // 32 KB
    __shared__ int   tokl[64];
    __shared__ float wgl[64];

    const int e = wl[blockIdx.x];
    if (e < 0) return;
    const int col  = e >> 24;
    const int nt   = (e >> 16) & 0xFF;
    const int base = e & 0xFFFF;

    const int tid = threadIdx.x;
    const int lane = tid & 63;
    const int wave = tid >> 6;
    const int wr = wave >> 1, wc = wave & 1;
    const int n0 = blockIdx.y * 64;

    if (tid < 64) {
        const int i = tid < nt ? tid : nt - 1;
        const int t = order[base + i];
        tokl[tid] = t;
        wgl[tid] = wgt[t];
    }
    __syncthreads();

    const int r0 = wave * 16 + (lane >> 3);
    const int r1 = r0 + 8;
    const int bl = (lane & 7) * 16;
    const int b0 = bl ^ ((r0 & 7) << 4);
    const int b1 = bl ^ ((r1 & 7) << 4);
    const char* gA0 = (const char*)Ag + (size_t)tokl[r0] * (D * 2) + b0;
    const char* gA1 = (const char*)Ag + (size_t)tokl[r1] * (D * 2) + b1;
    const size_t bbase = ((size_t)col * N + n0) * (D * 2);
    const char* gB0 = (const char*)BTg + bbase + (size_t)r0 * (D * 2) + b0;
    const char* gB1 = (const char*)BTg + bbase + (size_t)r1 * (D * 2) + b1;
    const int ldsWo = wave * 2048;

    const int mrow = wr * 32 + (lane & 15);
    const int nrow = wc * 32 + (lane & 15);
    const int kb0 = (lane >> 4) * 16;
    const int swm = (mrow & 7) << 4;
    const int swn = (nrow & 7) << 4;

    f32x4 acc[2][2] = {};
    {
        char* lA = (char*)AB[0][0] + ldsWo;
        char* lB = (char*)AB[0][1] + ldsWo;
        gload16(gA0, lA); gload16(gA1, lA + 1024);
        gload16(gB0, lB); gload16(gB1, lB + 1024);
    }
    __syncthreads();
    for (int kk = 0; kk < D / 64; ++kk) {
        const int cur = kk & 1;
        if (kk + 1 < D / 64) {
            const int ko = (kk + 1) * 128;
            char* lA = (char*)AB[cur ^ 1][0] + ldsWo;
            char* lB = (char*)AB[cur ^ 1][1] + ldsWo;
            gload16(gA0 + ko, lA); gload16(gA1 + ko, lA + 1024);
            gload16(gB0 + ko, lB); gload16(gB1 + ko, lB + 1024);
        }
        const char* As = (const char*)AB[cur][0];
        const char* Bs = (const char*)AB[cur][1];
        #pragma unroll
        for (int ks = 0; ks < 2; ++ks) {
            const int kb = kb0 + ks * 64;
            bf16x8 aF[2], bF[2];
            #pragma unroll
            for (int i = 0; i < 2; ++i)
                aF[i] = *(const bf16x8*)(As + (mrow + i * 16) * 128 + (kb ^ swm));
            #pragma unroll
            for (int j = 0; j < 2; ++j)
                bF[j] = *(const bf16x8*)(Bs + (nrow + j * 16) * 128 + (kb ^ swn));
            #pragma unroll
            for (int i = 0; i < 2; ++i)
                #pragma unroll
                for (int j = 0; j < 2; ++j)
                    acc[i][j] = __builtin_amdgcn_mfma_f32_16x16x32_bf16(
                                    aF[i], bF[j], acc[i][j], 0, 0, 0);
        }
        __syncthreads();
    }

    const int crow = (lane >> 4) * 4;
    const int ccol = lane & 15;
    #pragma unroll
    for (int i = 0; i < 2; ++i)
        #pragma unroll
        for (int j = 0; j < 2; ++j) {
            const int n = n0 + wc * 32 + j * 16 + ccol;
            const float bb = bias[col * N + n];
            #pragma unroll
            for (int r = 0; r < 4; ++r) {
                const int il = wr * 32 + i * 16 + crow + r;
                if (il < nt) {
                    const float v = gelu_exact(acc[i][j][r] + bb) * wgl[il];
                    outb[(size_t)(base + il) * N + n] = f2bf(v);
                }
            }
        }
}

// ---------------------------------------------------------------------------
// column GEMM2 (proj): 64(m) x 128(n) tile, K=256 (4 steps), dbuf gload.
// A = actb slots (contiguous), B = pwT. Writes ybuf[slot] = bf16(acc + pb).
// Residual + permutation live in ln_kernel.
// ---------------------------------------------------------------------------
__global__ __launch_bounds__(256) void proj_kernel(
        const short* __restrict__ Ag, const short* __restrict__ BTg,
        const float* __restrict__ bias, const int* __restrict__ wl,
        short* __restrict__ ybufb) {
    __shared__ short AB[2][(64 + 128) * 64];  // 48 KB (A 8KB + B 16KB per buf)
    const int e = wl[blockIdx.x];
    if (e < 0) return;
    const int col  = e >> 24;
    const int nt   = (e >> 16) & 0xFF;
    const int base = e & 0xFFFF;

    const int tid = threadIdx.x;
    const int lane = tid & 63;
    const int wave = tid >> 6;
    const int wr = wave >> 1, wc = wave & 1;
    const int n0 = blockIdx.y * 128;

    const int rl = lane >> 3;
    const int bl = (lane & 7) * 16;
    const int rA0 = wave * 16 + rl;
    const int rA1 = rA0 + 8;
    const char* gA0 = (const char*)Ag
        + (size_t)(base + min(rA0, nt - 1)) * (N * 2) + (bl ^ ((rA0 & 7) << 4));
    const char* gA1 = (const char*)Ag
        + (size_t)(base + min(rA1, nt - 1)) * (N * 2) + (bl ^ ((rA1 & 7) << 4));
    const size_t bbase = ((size_t)col * D + n0) * (N * 2);
    const char* gBh[4];
    #pragma unroll
    for (int h = 0; h < 4; ++h) {
        const int r = wave * 32 + h * 8 + rl;
        gBh[h] = (const char*)BTg + bbase + (size_t)r * (N * 2) + (bl ^ ((r & 7) << 4));
    }

    const int kb0 = (lane >> 4) * 16;

    f32x4 acc[2][4] = {};
    {
        char* Ab = (char*)AB[0];
        char* Bb = (char*)AB[0] + 8192;
        gload16(gA0, Ab + wave * 2048);
        gload16(gA1, Ab + wave * 2048 + 1024);
        #pragma unroll
        for (int h = 0; h < 4; ++h) gload16(gBh[h], Bb + (wave * 32 + h * 8) * 128);
    }
    __syncthreads();
    #pragma unroll
    for (int kk = 0; kk < N / 64; ++kk) {
        const int cur = kk & 1;
        if (kk + 1 < N / 64) {
            const int ko = (kk + 1) * 128;
            char* Ab = (char*)AB[cur ^ 1];
            char* Bb = (char*)AB[cur ^ 1] + 8192;
            gload16(gA0 + ko, Ab + wave * 2048);
            gload16(gA1 + ko, Ab + wave * 2048 + 1024);
            #pragma unroll
            for (int h = 0; h < 4; ++h) gload16(gBh[h] + ko, Bb + (wave * 32 + h * 8) * 128);
        }
        const char* As = (const char*)AB[cur];
        const char* Bs = As + 8192;
        #pragma unroll
        for (int ks = 0; ks < 2; ++ks) {
            const int kb = kb0 + ks * 64;
            bf16x8 aF[2], bF[4];
            #pragma unroll
            for (int i = 0; i < 2; ++i) {
                const int m = wr * 32 + i * 16 + (lane & 15);
                aF[i] = *(const bf16x8*)(As + m * 128 + (kb ^ ((m & 7) << 4)));
            }
            #pragma unroll
            for (int j = 0; j < 4; ++j) {
                const int n = wc * 64 + j * 16 + (lane & 15);
                bF[j] = *(const bf16x8*)(Bs + n * 128 + (kb ^ ((n & 7) << 4)));
            }
            #pragma unroll
            for (int i = 0; i < 2; ++i)
                #pragma unroll
                for (int j = 0; j < 4; ++j)
                    acc[i][j] = __builtin_amdgcn_mfma_f32_16x16x32_bf16(
                                    aF[i], bF[j], acc[i][j], 0, 0, 0);
        }
        __syncthreads();
    }

    const int crow = (lane >> 4) * 4;
    const int ccol = lane & 15;
    #pragma unroll
    for (int i = 0; i < 2; ++i)
        #pragma unroll
        for (int j = 0; j < 4; ++j) {
            const int dcol = n0 + wc * 64 + j * 16 + ccol;
            const float bb = bias[dcol];
            #pragma unroll
            for (int r = 0; r < 4; ++r) {
                const int il = wr * 32 + i * 16 + crow + r;
                if (il < nt)
                    ybufb[(size_t)(base + il) * D + dcol] = f2bf(acc[i][j][r] + bb);
            }
        }
}

// ---------------------------------------------------------------------------
// route: weights-in-registers, activations streamed coalesced (round-4 winner)
// ---------------------------------------------------------------------------
__global__ __launch_bounds__(256) void route_kernel(
        const float* __restrict__ x, const short* __restrict__ Hb,
        const float* __restrict__ col_emb, const float* __restrict__ cnorm,
        const float* __restrict__ w2, const float* __restrict__ b2,
        int* __restrict__ idx, float* __restrict__ wgt) {
    __shared__ float P[256][33];
    __shared__ float Q[8][33];
    __shared__ float SSW[4];
    __shared__ float FL[RT_T][34];
    const int tid = threadIdx.x;
    const int lane = tid & 63;
    const int t0 = blockIdx.x * RT_T;
    const int swz = (tid & 7) << 2;

    float4 ce[C];
    #pragma unroll
    for (int c = 0; c < C; ++c)
        ce[c] = *(const float4*)&col_emb[c * D + tid * 4];
    float w2r[2][C];
    #pragma unroll
    for (int r2 = 0; r2 < 2; ++r2)
        #pragma unroll
        for (int cq = 0; cq < 4; ++cq) {
            const float4 v = *(const float4*)&w2[(tid * 2 + r2) * C + cq * 4];
            w2r[r2][cq * 4 + 0] = v.x; w2r[r2][cq * 4 + 1] = v.y;
            w2r[r2][cq * 4 + 2] = v.z; w2r[r2][cq * 4 + 3] = v.w;
        }

    for (int ti = 0; ti < RT_T; ++ti) {
        const int t = t0 + ti;
        const float4 xv = *(const float4*)&x[(size_t)t * D + tid * 4];
        const unsigned hu = *(const unsigned*)&Hb[(size_t)t * DH + tid * 2];
        const float h0 = bf2f((short)(hu & 0xffff));
        const float h1 = bf2f((short)(hu >> 16));
        float pv[32];
        #pragma unroll
        for (int c = 0; c < C; ++c)
            pv[c] = xv.x * ce[c].x + xv.y * ce[c].y + xv.z * ce[c].z + xv.w * ce[c].w;
        #pragma unroll
        for (int c = 0; c < C; ++c)
            pv[C + c] = h0 * w2r[0][c] + h1 * w2r[1][c];
        float ssp = xv.x * xv.x + xv.y * xv.y + xv.z * xv.z + xv.w * xv.w;
        #pragma unroll
        for (int off = 32; off; off >>= 1) ssp += __shfl_xor(ssp, off);
        if (lane == 0) SSW[tid >> 6] = ssp;
        #pragma unroll
        for (int c = 0; c < 32; ++c)
            P[tid][c ^ swz] = pv[c];
        __syncthreads();
        {
            const int v = tid & 31, jj = tid >> 5;
            float s = 0.f;
            #pragma unroll
            for (int k = 0; k < 32; ++k) {
                const int row = jj * 32 + k;
                s += P[row][v ^ ((row & 7) << 2)];
            }
            Q[jj][v] = s;
        }
        __syncthreads();
        if (tid < 32) {
            float f = 0.f;
            #pragma unroll
            for (int j2 = 0; j2 < 8; ++j2) f += Q[j2][tid];
            FL[ti][tid] = f;
        } else if (tid == 32) {
            FL[ti][32] = SSW[0] + SSW[1] + SSW[2] + SSW[3];
        }
        __syncthreads();
    }

    if (tid < RT_T) {
        const int t = t0 + tid;
        const float xn = fmaxf(sqrtf(FL[tid][32]), 1e-12f);
        float logit[C];
        #pragma unroll
        for (int c = 0; c < C; ++c)
            logit[c] = FL[tid][c] / (xn * cnorm[c])
                     + sigmoidf_(FL[tid][C + c] + b2[c]);
        float mx = logit[0]; int am = 0;
        #pragma unroll
        for (int c = 1; c < C; ++c)
            if (logit[c] > mx) { mx = logit[c]; am = c; }
        float se = 0.f;
        #pragma unroll
        for (int c = 0; c < C; ++c) se += expf(logit[c] - mx);
        idx[t] = am;
        wgt[t] = 1.f / se;
    }
}

// ---------------------------------------------------------------------------
// histogram (ballot-based) + prefix + packed worklist (single block)
// ---------------------------------------------------------------------------
__global__ __launch_bounds__(256) void hist_kernel(const int* __restrict__ idx,
        int* __restrict__ cursor, int* __restrict__ wl) {
    __shared__ int h[C];
    const int tid = threadIdx.x;
    const int lane = tid & 63;
    const int wave = tid >> 6;
    if (tid < C) h[tid] = 0;
    for (int i = tid; i < WLG; i += 256) wl[i] = -1;
    __syncthreads();
    int cnt = 0;
    for (int t0 = wave * 64; t0 < TOK; t0 += 256) {
        const int c = idx[t0 + lane];
        #pragma unroll
        for (int cc = 0; cc < C; ++cc) {
            const unsigned long long m = __ballot(c == cc);
            if (lane == cc) cnt += (int)__popcll(m);
        }
    }
    if (lane < C) atomicAdd(&h[lane], cnt);
    __syncthreads();
    if (tid == 0) {
        int s = 0;
        int slots[8] = {0, 0, 0, 0, 0, 0, 0, 0};
        for (int c = 0; c < C; ++c) {
            cursor[c] = s;
            for (int st = 0; st < h[c]; st += 64) {
                const int ntg = min(64, h[c] - st);
                int b = c & 7;
                while (slots[b] >= BCAP) b = (b + 1) & 7;
                wl[slots[b] * 8 + b] = (c << 24) | (ntg << 16) | (s + st);
                slots[b]++;
            }
            s += h[c];
        }
    }
}

// ---------------------------------------------------------------------------
// scatter: block-local ranges -> 16 global atomics per block
// ---------------------------------------------------------------------------
__global__ __launch_bounds__(256) void scatter_kernel(const int* __restrict__ idx,
        int* __restrict__ cursor, int* __restrict__ order) {
    __shared__ int lh[C];
    __shared__ int lbase[C];
    const int tid = threadIdx.x;
    const int t = blockIdx.x * 256 + tid;
    if (tid < C) lh[tid] = 0;
    __syncthreads();
    const int c = idx[t];
    const int p = atomicAdd(&lh[c], 1);
    __syncthreads();
    if (tid < C) lbase[tid] = atomicAdd(&cursor[tid], lh[tid]);
    __syncthreads();
    order[lbase[c] + p] = t;
}

// ---------------------------------------------------------------------------
// layernorm + residual + slot->token permutation:
// block s: row = order[s]; y = bf2f(ybufb[s]) + bf2f(xb[row]); out[row] = LN(y)
// (residual uses bf16-rounded x: halves the x-read; drift << threshold)
// ---------------------------------------------------------------------------
__global__ __launch_bounds__(256) void ln_kernel(const short* __restrict__ ybufb,
        const short* __restrict__ xb, const int* __restrict__ order,
        const float* __restrict__ g, const float* __restrict__ b,
        float* __restrict__ out) {
    __shared__ float wr_[4], wr2[4];
    const int s0 = blockIdx.x, tid = threadIdx.x;
    const int row = order[s0];
    const short4 ys = *(const short4*)&ybufb[(size_t)s0 * D + tid * 4];
    const short4 xs = *(const short4*)&xb[(size_t)row * D + tid * 4];
    float4 v;
    v.x = bf2f(ys.x) + bf2f(xs.x); v.y = bf2f(ys.y) + bf2f(xs.y);
    v.z = bf2f(ys.z) + bf2f(xs.z); v.w = bf2f(ys.w) + bf2f(xs.w);
    float s = v.x + v.y + v.z + v.w;
    float s2 = v.x * v.x + v.y * v.y + v.z * v.z + v.w * v.w;
    for (int off = 32; off; off >>= 1) { s += __shfl_xor(s, off); s2 += __shfl_xor(s2, off); }
    if ((tid & 63) == 0) { wr_[tid >> 6] = s; wr2[tid >> 6] = s2; }
    __syncthreads();
    const float sum = wr_[0] + wr_[1] + wr_[2] + wr_[3];
    const float sum2 = wr2[0] + wr2[1] + wr2[2] + wr2[3];
    const float mu = sum * (1.f / D);
    const float var = sum2 * (1.f / D) - mu * mu;
    const float inv = rsqrtf(var + 1e-5f);
    const float4 g4 = *(const float4*)&g[tid * 4];
    const float4 b4 = *(const float4*)&b[tid * 4];
    float4 o;
    o.x = (v.x - mu) * inv * g4.x + b4.x;
    o.y = (v.y - mu) * inv * g4.y + b4.y;
    o.z = (v.z - mu) * inv * g4.z + b4.z;
    o.w = (v.w - mu) * inv * g4.w + b4.w;
    *(float4*)&out[(size_t)row * D + tid * 4] = o;
}

// ---------------------------------------------------------------------------
extern "C" void kernel_launch(void* const* d_in, const int* in_sizes, int n_in,
                              void* d_out, int out_size, void* d_ws, size_t ws_size,
                              hipStream_t stream) {
    const float* x       = (const float*)d_in[0];
    const float* col_emb = (const float*)d_in[1];
    const float* gate_w1 = (const float*)d_in[2];
    const float* gate_b1 = (const float*)d_in[3];
    const float* gate_w2 = (const float*)d_in[4];
    const float* gate_b2 = (const float*)d_in[5];
    const float* W_cols  = (const float*)d_in[6];
    const float* b_cols  = (const float*)d_in[7];
    const float* proj_w  = (const float*)d_in[8];
    const float* proj_b  = (const float*)d_in[9];
    const float* ln_g    = (const float*)d_in[10];
    const float* ln_b    = (const float*)d_in[11];
    float* out = (float*)d_out;

    char* w = (char*)d_ws;
    short* xb    = (short*)w;  w += (size_t)TOK * D * 2;           // 16 MB
    short* Hb    = (short*)w;  w += (size_t)TOK * DH * 2;          //  8 MB
    short* actb  = (short*)w;  w += (size_t)TOK * N * 2 + 65536;   //  4 MB + slack
    short* w1T   = (short*)w;  w += (size_t)DH * D * 2;            //  1 MB
    short* WcT   = (short*)w;  w += (size_t)C * N * D * 2;         //  8 MB
    short* pwT   = (short*)w;  w += (size_t)C * D * N * 2;         //  8 MB
    short* ybufb = (short*)w;  w += (size_t)TOK * D * 2;           // 16 MB
    float* wgt   = (float*)w;  w += TOK * 4;
    float* cnorm = (float*)w;  w += 64;
    int*   idx   = (int*)w;    w += TOK * 4;
    int*   order = (int*)w;    w += TOK * 4;
    int*   cursor= (int*)w;    w += 64;
    int*   wl    = (int*)w;    w += WLG * 4;

    hipLaunchKernelGGL(prep_all_kernel, dim3(4225), dim3(256), 0, stream,
                       x, col_emb, gate_w1, W_cols, proj_w,
                       xb, w1T, WcT, pwT, cnorm);
    hipLaunchKernelGGL(gate_mfma_kernel, dim3(TOK / 128, DH / 64), dim3(256), 0, stream,
                       xb, w1T, gate_b1, Hb);
    hipLaunchKernelGGL(route_kernel, dim3(TOK / RT_T), dim3(256), 0, stream,
                       x, Hb, col_emb, cnorm, gate_w2, gate_b2, idx, wgt);
    hipLaunchKernelGGL(hist_kernel, dim3(1), dim3(256), 0, stream, idx, cursor, wl);
    hipLaunchKernelGGL(scatter_kernel, dim3(TOK / 256), dim3(256), 0, stream,
                       idx, cursor, order);
    hipLaunchKernelGGL(col1_kernel, dim3(WLG, N / 64), dim3(256), 0, stream,
                       xb, WcT, b_cols, order, wgt, wl, actb);
    hipLaunchKernelGGL(proj_kernel, dim3(WLG, D / 128), dim3(256), 0, stream,
                       actb, pwT, proj_b, wl, ybufb);
    hipLaunchKernelGGL(ln_kernel, dim3(TOK), dim3(256), 0, stream,
                       ybufb, xb, order, ln_g, ln_b, out);
}